// Round 16
// baseline (320.042 us; speedup 1.0000x reference)
//
#include <hip/hip_runtime.h>
#include <math.h>

#define NPAR 8
#define DIM  16
#define HID  128
#define BATCH 4096

typedef __attribute__((ext_vector_type(8))) short short8;
typedef __attribute__((ext_vector_type(4))) float f32x4;

// Packed A-fragment arrays (bf16, 3-way split hi/mid/lo), static device memory.
// slots 0..5 = {PF2, PB2, PF3, PB3, PF4, PB4}; per slot (halfs):
//   slot stride 49152 = part(3)x16384 = chunk(4)x4096 = mt(8)x512 = lane(64)x8
// W1^T region at 294912: part stride 2048, chunk 512, single mt. Total 301056 halfs.
__device__ __align__(16) unsigned short g_fr[301056];

__device__ __forceinline__ float sigf(float z){ return 1.0f/(1.0f+__expf(-z)); }
__device__ __forceinline__ float spf(float z){ return fmaxf(z,0.0f)+log1pf(__expf(-fabsf(z))); }
__device__ __forceinline__ unsigned short bf16rne(float v){
  unsigned u = __float_as_uint(v);
  u += 0x7FFFu + ((u>>16)&1u);
  return (unsigned short)(u>>16);
}
__device__ __forceinline__ float bf2f(unsigned short h){ return __uint_as_float(((unsigned)h)<<16); }

__global__ void pack_weights(const float* __restrict__ W1, const float* __restrict__ W2,
                             const float* __restrict__ W3, const float* __restrict__ W4){
  int t = blockIdx.x*blockDim.x + threadIdx.x;
  if (t >= 301056) return;
  float val; int p;
  if (t < 294912){
    int slot = t/49152, r = t%49152;
    p = r/16384; int r2 = r%16384;
    int c = r2/4096, r3 = r2%4096;
    int mt = r3/512, r4 = r3%512;
    int lane = r4/8, i = r4%8;
    int m = mt*16 + (lane&15);
    int k = c*32 + (lane>>4)*8 + i;
    const float* W = (slot>>1)==0 ? W2 : ((slot>>1)==1 ? W3 : W4);
    val = ((slot&1)==0) ? W[m*HID + k] : W[k*HID + m];   // even: A=W, odd: A=W^T
  } else {
    int idx = t - 294912;
    p = idx/2048; int r = idx%2048;
    int c = r/512, r2 = r%512;
    int lane = r2/8, i = r2%8;
    int md = lane&15;
    int k = c*32 + (lane>>4)*8 + i;
    val = W1[k*DIM + md];                                 // A = W1^T
  }
  unsigned short h = bf16rne(val); float rem  = val - bf2f(h);
  unsigned short m2 = bf16rne(rem); float rem2 = rem - bf2f(m2);
  unsigned short lo = bf16rne(rem2);
  g_fr[t] = (p==0)? h : (p==1)? m2 : lo;
}

// Mixed-split MFMA GEMV: C[mt][reg] accumulates 6 split-products.
// B-frags from LDS H^T (3 parts, row stride 136 halfs, part stride 2176).
template<int NMT, int PSTR, int CSTR>
__device__ __forceinline__ void gemv_mfma(const unsigned short* __restrict__ fr,
                                          const unsigned short* __restrict__ hl,
                                          int lane, f32x4* acc){
  const int n = lane & 15, kg = lane >> 4;
#pragma unroll
  for (int mt=0; mt<NMT; ++mt) acc[mt] = (f32x4){0.f,0.f,0.f,0.f};
#pragma unroll
  for (int c=0;c<4;++c){
    const int hoff = n*136 + c*32 + kg*8;
    short8 Bh = *(const short8*)(hl + hoff);
    short8 Bm = *(const short8*)(hl + 2176 + hoff);
    short8 Bl = *(const short8*)(hl + 4352 + hoff);
#pragma unroll
    for (int mt=0; mt<NMT; ++mt){
      const unsigned short* ab = fr + c*CSTR + mt*512 + lane*8;
      short8 Ah = *(const short8*)(ab);
      short8 Am = *(const short8*)(ab + PSTR);
      short8 Al = *(const short8*)(ab + 2*PSTR);
      acc[mt] = __builtin_amdgcn_mfma_f32_16x16x32_bf16(Ah,Bh,acc[mt],0,0,0);
      acc[mt] = __builtin_amdgcn_mfma_f32_16x16x32_bf16(Ah,Bm,acc[mt],0,0,0);
      acc[mt] = __builtin_amdgcn_mfma_f32_16x16x32_bf16(Am,Bh,acc[mt],0,0,0);
      acc[mt] = __builtin_amdgcn_mfma_f32_16x16x32_bf16(Ah,Bl,acc[mt],0,0,0);
      acc[mt] = __builtin_amdgcn_mfma_f32_16x16x32_bf16(Am,Bm,acc[mt],0,0,0);
      acc[mt] = __builtin_amdgcn_mfma_f32_16x16x32_bf16(Al,Bh,acc[mt],0,0,0);
    }
  }
}

// Split 4 row-consecutive values 3-way and store as 3x b64 into H^T.
__device__ __forceinline__ void write4(unsigned short* base, float v0, float v1, float v2, float v3){
#pragma unroll
  for (int p=0;p<3;++p){
    unsigned short h0=bf16rne(v0), h1=bf16rne(v1), h2=bf16rne(v2), h3=bf16rne(v3);
    uint2 w; w.x = (unsigned)h0 | ((unsigned)h1<<16); w.y = (unsigned)h2 | ((unsigned)h3<<16);
    *(uint2*)(base + p*2176) = w;
    v0 -= bf2f(h0); v1 -= bf2f(h1); v2 -= bf2f(h2); v3 -= bf2f(h3);
  }
}

__global__ __launch_bounds__(64)
void lnn_main(const float* __restrict__ x, const float* __restrict__ W1,
              const float* __restrict__ b1, const float* __restrict__ b2,
              const float* __restrict__ b3, const float* __restrict__ b4,
              const float* __restrict__ W5, float* __restrict__ out){
  const int l = threadIdx.x;
  const int sid = blockIdx.x;
  const int n = l & 15, kg = l >> 4;
  const int l48 = l & 48;

  __shared__ __align__(16) unsigned short Hl[6528];  // 3 parts x 16 rows x 136 halfs
  __shared__ float sA[3*128];                        // s1@0, s2@128, s3@256
  __shared__ float xsl[16];

  if (l < DIM) xsl[l] = x[sid*DIM + l];
  __syncthreads();

  // ---- Phase 1 (VALU): layer 1; write H^T rows v=0..8 (3 parts) + s1 ----
  {
    const int o = l & 31, kh = l >> 5;
    const int ja = o + 64*kh, jb = ja + 32;
    const float4* W1v = (const float4*)W1;
    float4 a0 = W1v[ja*4+0], a1 = W1v[ja*4+1], a2 = W1v[ja*4+2], a3 = W1v[ja*4+3];
    float4 c0 = W1v[jb*4+0], c1 = W1v[jb*4+1], c2 = W1v[jb*4+2], c3 = W1v[jb*4+3];
    float z1a = b1[ja], z1b = b1[jb];
    z1a = fmaf(a0.x, xsl[0],  z1a); z1a = fmaf(a0.y, xsl[1],  z1a);
    z1a = fmaf(a0.z, xsl[2],  z1a); z1a = fmaf(a0.w, xsl[3],  z1a);
    z1a = fmaf(a1.x, xsl[4],  z1a); z1a = fmaf(a1.y, xsl[5],  z1a);
    z1a = fmaf(a1.z, xsl[6],  z1a); z1a = fmaf(a1.w, xsl[7],  z1a);
    z1a = fmaf(a2.x, xsl[8],  z1a); z1a = fmaf(a2.y, xsl[9],  z1a);
    z1a = fmaf(a2.z, xsl[10], z1a); z1a = fmaf(a2.w, xsl[11], z1a);
    z1a = fmaf(a3.x, xsl[12], z1a); z1a = fmaf(a3.y, xsl[13], z1a);
    z1a = fmaf(a3.z, xsl[14], z1a); z1a = fmaf(a3.w, xsl[15], z1a);
    z1b = fmaf(c0.x, xsl[0],  z1b); z1b = fmaf(c0.y, xsl[1],  z1b);
    z1b = fmaf(c0.z, xsl[2],  z1b); z1b = fmaf(c0.w, xsl[3],  z1b);
    z1b = fmaf(c1.x, xsl[4],  z1b); z1b = fmaf(c1.y, xsl[5],  z1b);
    z1b = fmaf(c1.z, xsl[6],  z1b); z1b = fmaf(c1.w, xsl[7],  z1b);
    z1b = fmaf(c2.x, xsl[8],  z1b); z1b = fmaf(c2.y, xsl[9],  z1b);
    z1b = fmaf(c2.z, xsl[10], z1b); z1b = fmaf(c2.w, xsl[11], z1b);
    z1b = fmaf(c3.x, xsl[12], z1b); z1b = fmaf(c3.y, xsl[13], z1b);
    z1b = fmaf(c3.z, xsl[14], z1b); z1b = fmaf(c3.w, xsl[15], z1b);
    float s1a = sigf(z1a), s1b = sigf(z1b);
    sA[ja] = s1a; sA[jb] = s1b;
    float wa[8] = {a2.x,a2.y,a2.z,a2.w,a3.x,a3.y,a3.z,a3.w};
    float wb[8] = {c2.x,c2.y,c2.z,c2.w,c3.x,c3.y,c3.z,c3.w};
    float vA[9], vB[9];
    vA[0] = spf(z1a); vB[0] = spf(z1b);
#pragma unroll
    for (int i=0;i<8;++i){ vA[1+i] = s1a*wa[i]; vB[1+i] = s1b*wb[i]; }
#pragma unroll
    for (int v=0;v<9;++v){
      float ra = vA[v], rb = vB[v];
#pragma unroll
      for (int p=0;p<3;++p){
        unsigned short ha = bf16rne(ra); Hl[p*2176 + v*136 + ja] = ha; ra -= bf2f(ha);
        unsigned short hb = bf16rne(rb); Hl[p*2176 + v*136 + jb] = hb; rb -= bf2f(hb);
      }
    }
  }
  __syncthreads();

  f32x4 acc[8];
  float t2c[8][4], t3c[8][4];

  // ---- Phase 2: W2 forward (slot 0) ----
  gemv_mfma<8,16384,4096>(g_fr + 0*49152, Hl, l, acc);
  {
    const float4* bv = (const float4*)b2;
#pragma unroll
    for (int mt=0; mt<8; ++mt){
      float4 bias = bv[mt*4+kg];
      float ov[4];
#pragma unroll
      for (int reg=0; reg<4; ++reg){
        float c0 = __shfl(acc[mt][reg], l48);
        float z  = c0 + ((const float*)&bias)[reg];
        float s  = sigf(z);
        t2c[mt][reg] = acc[mt][reg];
        ov[reg] = (n==0) ? spf(z) : s*acc[mt][reg];
        if (n==0) sA[128 + mt*16 + kg*4 + reg] = s;
      }
      if (n<9) write4(Hl + n*136 + mt*16 + kg*4, ov[0],ov[1],ov[2],ov[3]);
    }
  }
  __syncthreads();

  // ---- Phase 3: W3 forward (slot 2) ----
  gemv_mfma<8,16384,4096>(g_fr + 2*49152, Hl, l, acc);
  {
    const float4* bv = (const float4*)b3;
#pragma unroll
    for (int mt=0; mt<8; ++mt){
      float4 bias = bv[mt*4+kg];
      float ov[4];
#pragma unroll
      for (int reg=0; reg<4; ++reg){
        float c0 = __shfl(acc[mt][reg], l48);
        float z  = c0 + ((const float*)&bias)[reg];
        float s  = sigf(z);
        t3c[mt][reg] = acc[mt][reg];
        ov[reg] = (n==0) ? spf(z) : s*acc[mt][reg];
        if (n==0) sA[256 + mt*16 + kg*4 + reg] = s;
      }
      if (n<9) write4(Hl + n*136 + mt*16 + kg*4, ov[0],ov[1],ov[2],ov[3]);
    }
  }
  __syncthreads();

  // ---- Phase 4+5: W4 forward (slot 4) + head ----
  gemv_mfma<8,16384,4096>(g_fr + 4*49152, Hl, l, acc);
  {
    const float4* bv  = (const float4*)b4;
    const float4* w5v = (const float4*)W5;
#pragma unroll
    for (int mt=0; mt<8; ++mt){
      float4 bias = bv[mt*4+kg];
      float4 w5q  = w5v[mt*4+kg];
      float ov[4];
#pragma unroll
      for (int reg=0; reg<4; ++reg){
        float c0 = __shfl(acc[mt][reg], l48);
        float z  = c0 + ((const float*)&bias)[reg];
        float s  = sigf(z);
        float w5r = ((const float*)&w5q)[reg];
        ov[reg] = (n==0) ? w5r*s : (w5r*s*(1.0f-s))*acc[mt][reg];
      }
      if (n<9) write4(Hl + n*136 + mt*16 + kg*4, ov[0],ov[1],ov[2],ov[3]);
    }
  }
  __syncthreads();

  // ---- Phase 6: backward through W4^T (slot 5); s3 + t3 ----
  gemv_mfma<8,16384,4096>(g_fr + 5*49152, Hl, l, acc);
  {
#pragma unroll
    for (int mt=0; mt<8; ++mt){
      float ov[4];
#pragma unroll
      for (int reg=0; reg<4; ++reg){
        int j = mt*16 + kg*4 + reg;
        float g   = __shfl(acc[mt][reg], l48);
        float sld = sA[256 + j];
        float d   = sld*(1.0f-sld)*g;
        ov[reg] = (n==0) ? g*sld : fmaf(acc[mt][reg], sld, d*t3c[mt][reg]);
      }
      if (n<9) write4(Hl + n*136 + mt*16 + kg*4, ov[0],ov[1],ov[2],ov[3]);
    }
  }
  __syncthreads();

  // ---- Phase 7: backward through W3^T (slot 3); s2 + t2 ----
  gemv_mfma<8,16384,4096>(g_fr + 3*49152, Hl, l, acc);
  {
#pragma unroll
    for (int mt=0; mt<8; ++mt){
      float ov[4];
#pragma unroll
      for (int reg=0; reg<4; ++reg){
        int j = mt*16 + kg*4 + reg;
        float g   = __shfl(acc[mt][reg], l48);
        float sld = sA[128 + j];
        float d   = sld*(1.0f-sld)*g;
        ov[reg] = (n==0) ? g*sld : fmaf(acc[mt][reg], sld, d*t2c[mt][reg]);
      }
      if (n<9) write4(Hl + n*136 + mt*16 + kg*4, ov[0],ov[1],ov[2],ov[3]);
    }
  }
  __syncthreads();

  // ---- Phase 8: backward through W2^T (slot 1); s1 + W1 tangent cols ----
  gemv_mfma<8,16384,4096>(g_fr + 1*49152, Hl, l, acc);
  {
    const int col = (n>=1 && n<9) ? (7+n) : 7;   // W1[:, 8+(n-1)]
#pragma unroll
    for (int mt=0; mt<8; ++mt){
      float ov[4];
#pragma unroll
      for (int reg=0; reg<4; ++reg){
        int j = mt*16 + kg*4 + reg;
        float g   = __shfl(acc[mt][reg], l48);
        float sld = sA[j];
        float d   = sld*(1.0f-sld)*g;
        float w1c = W1[j*DIM + col];
        ov[reg] = (n==0) ? g*sld : fmaf(acc[mt][reg], sld, d*w1c);
      }
      if (n<9) write4(Hl + n*136 + mt*16 + kg*4, ov[0],ov[1],ov[2],ov[3]);
    }
  }
  __syncthreads();

  // ---- Phase 9: H rows + J via W1^T (single M-tile) ----
  f32x4 a9[1];
  gemv_mfma<1,2048,512>(g_fr + 294912, Hl, l, a9);
  float q0 = a9[0][0], q1 = a9[0][1], q2 = a9[0][2], q3 = a9[0][3];

  // ---- Phase 10: gather B/C/J from C-layout; f32 Jacobi pinv solve ----
  {
    const int r = l >> 3, c = l & 7;
    int srcB = ((8+c)>>2)*16 + 1 + r;                 // C[8+c][1+r]
    float g0=__shfl(q0,srcB), g1=__shfl(q1,srcB), g2=__shfl(q2,srcB), g3=__shfl(q3,srcB);
    int rb = c & 3;
    float Bv = rb==0?g0: rb==1?g1: rb==2?g2: g3;
    int srcC = (c>>2)*16 + 1 + r;                     // C[c][1+r]
    float h0=__shfl(q0,srcC), h1=__shfl(q1,srcC), h2=__shfl(q2,srcC), h3=__shfl(q3,srcC);
    float Cv = rb==0?h0: rb==1?h1: rb==2?h2: h3;
    int srcJ = (r>>2)*16;                             // C[r][0]
    float e0=__shfl(q0,srcJ), e1=__shfl(q1,srcJ), e2=__shfl(q2,srcJ), e3=__shfl(q3,srcJ);
    int rj = r & 3;
    float Jr = rj==0?e0: rj==1?e1: rj==2?e2: e3;

    float p0 = Cv * xsl[8 + c];
    p0 += __shfl_xor(p0, 1); p0 += __shfl_xor(p0, 2); p0 += __shfl_xor(p0, 4);
    float rhs = Jr - p0;

    float Bt = __shfl(Bv, c*8 + r);
    float Am = 0.5f*(Bv + Bt);
    float Vm = (r == c) ? 1.0f : 0.0f;

    for (int sweep = 0; sweep < 4; ++sweep) {
#pragma unroll
      for (int rr = 0; rr < 7; ++rr) {
        int pc = (c == 7) ? rr : ((c == rr) ? 7 : (2*rr + 7 - c) % 7);
        int cp = min(c, pc), cq = max(c, pc);
        float App = __shfl(Am, cp*8+cp);
        float Aqq = __shfl(Am, cq*8+cq);
        float Apq = __shfl(Am, cp*8+cq);
        float tau = (Aqq - App) / (2.0f*Apq);
        float tt  = (tau >= 0.0f ? 1.0f : -1.0f) / (fabsf(tau) + sqrtf(1.0f + tau*tau));
        float cth = 1.0f / sqrtf(1.0f + tt*tt);
        float sth = tt * cth;
        if (fabsf(Apq) < 1e-30f) { cth = 1.0f; sth = 0.0f; }
        float cthr = __shfl(cth, r*8+r);
        float sthr = __shfl(sth, r*8+r);
        float Arp = __shfl(Am, r*8+cp);
        float Arq = __shfl(Am, r*8+cq);
        float colv = (c == cp) ? (cth*Arp - sth*Arq) : (sth*Arp + cth*Arq);
        int pr2 = (r == 7) ? rr : ((r == rr) ? 7 : (2*rr + 7 - r) % 7);
        int rp = min(r, pr2), rq = max(r, pr2);
        float Mpc = __shfl(colv, rp*8+c);
        float Mqc = __shfl(colv, rq*8+c);
        Am = (r == rp) ? (cthr*Mpc - sthr*Mqc) : (sthr*Mpc + cthr*Mqc);
        float Vrp = __shfl(Vm, r*8+cp);
        float Vrq = __shfl(Vm, r*8+cq);
        Vm = (c == cp) ? (cth*Vrp - sth*Vrq) : (sth*Vrp + cth*Vrq);
      }
    }

    float lam_c = __shfl(Am, c*8 + c);
    float adiag = (r == c) ? fabsf(Am) : 0.0f;
#pragma unroll
    for (int off = 32; off; off >>= 1) adiag = fmaxf(adiag, __shfl_xor(adiag, off));
    float cutoff = 9.5367431640625e-06f * adiag;

    float pr = Vm * rhs;
    pr += __shfl_xor(pr, 8); pr += __shfl_xor(pr, 16); pr += __shfl_xor(pr, 32);
    float w = (fabsf(lam_c) > cutoff) ? (pr / lam_c) : 0.0f;
    float yr = Vm * w;
    yr += __shfl_xor(yr, 1); yr += __shfl_xor(yr, 2); yr += __shfl_xor(yr, 4);
    if (c == 0) out[sid*NPAR + r] = yr;
  }
}

extern "C" void kernel_launch(void* const* d_in, const int* in_sizes, int n_in,
                              void* d_out, int out_size, void* d_ws, size_t ws_size,
                              hipStream_t stream) {
  (void)in_sizes; (void)n_in; (void)out_size; (void)d_ws; (void)ws_size;
  const float* x  = (const float*)d_in[0];
  const float* W1 = (const float*)d_in[1];
  const float* b1 = (const float*)d_in[2];
  const float* W2 = (const float*)d_in[3];
  const float* b2 = (const float*)d_in[4];
  const float* W3 = (const float*)d_in[5];
  const float* b3 = (const float*)d_in[6];
  const float* W4 = (const float*)d_in[7];
  const float* b4 = (const float*)d_in[8];
  const float* W5 = (const float*)d_in[9];
  float* out = (float*)d_out;

  pack_weights<<<1176, 256, 0, stream>>>(W1, W2, W3, W4);
  lnn_main<<<BATCH, 64, 0, stream>>>(x, W1, b1, b2, b3, b4, W5, out);
}

// Round 19
// 225.480 us; speedup vs baseline: 1.4194x; 1.4194x over previous
//
#include <hip/hip_runtime.h>
#include <math.h>

#define NPAR 8
#define DIM  16
#define HID  128
#define BATCH 4096
#define VSTRF 132              // stride (floats) per 128-vector in LDS
#define NVEC 9                 // base + 8 tangent directions

typedef float v2f __attribute__((ext_vector_type(2)));

// Packed f32 weights (exact copies of f32 inputs) in static device memory.
// Layout (float offsets): PF2@0 PB2@16384 PF3@32768 PB3@49152 PF4@65536 PB4@81920 PB1@98304
// pos(jo,kr) = (((kr>>6)*16 + ((kr&63)>>2))*4 + (jo>>5))*128 + (jo&31)*4 + (kr&3)
__device__ float g_wsf[6*HID*HID + HID*DIM];

__device__ __forceinline__ float sigf(float z){ return 1.0f/(1.0f+__expf(-z)); }
__device__ __forceinline__ float spf(float z){ return fmaxf(z,0.0f)+log1pf(__expf(-fabsf(z))); }
__device__ __forceinline__ int posf(int jo, int kr){
  return (((kr>>6)*16 + ((kr&63)>>2))*4 + (jo>>5))*128 + (jo&31)*4 + (kr&3);
}

__global__ void pack_weights(const float* __restrict__ W1, const float* __restrict__ W2,
                             const float* __restrict__ W3, const float* __restrict__ W4) {
  int t = blockIdx.x*blockDim.x + threadIdx.x;
  if (t < 3*HID*HID) {
    int m = t/(HID*HID); int r = t%(HID*HID);
    int j = r/HID, k = r%HID;
    const float* W = (m==0)?W2:((m==1)?W3:W4);
    float w = W[j*HID+k];
    float* PF = g_wsf + m*2*HID*HID;
    float* PB = PF + HID*HID;
    PF[posf(j,k)] = w;
    PB[posf(k,j)] = w;
  } else {
    int r = t - 3*HID*HID;
    if (r < HID*DIM) {
      int k = r/DIM, m2 = r%DIM;
      g_wsf[6*HID*HID + (k>>2)*(DIM*4) + m2*4 + (k&3)] = W1[k*DIM+m2];
    }
  }
}

// All-f32 split-K fused 9-vector GEMV using packed f32 FMA over k-pairs.
// Lane (o,kh) covers k-half kh for outputs {o,o+32,o+64,o+96}; after the
// shfl_xor(32) reduction the lane keeps j_a = o+64*kh (zA), j_b = j_a+32 (zB).
__device__ __forceinline__ void gemv9f32(const float* __restrict__ Wbase,
    const float* __restrict__ bin, int o, int kh, float* zA, float* zB) {
  const float4* Wq = (const float4*)Wbase;
  const float* hb = bin + kh*64;
  v2f acc[4][NVEC];
#pragma unroll
  for (int jj=0;jj<4;++jj)
#pragma unroll
    for (int v=0;v<NVEC;++v) acc[jj][v] = (v2f){0.0f, 0.0f};
#pragma unroll 4
  for (int q=0;q<16;++q){
    int base = ((kh*16+q)*4)*32 + o;
    float4 w0 = Wq[base], w1 = Wq[base+32], w2 = Wq[base+64], w3 = Wq[base+96];
    v2f w0a={w0.x,w0.y}, w0b={w0.z,w0.w};
    v2f w1a={w1.x,w1.y}, w1b={w1.z,w1.w};
    v2f w2a={w2.x,w2.y}, w2b={w2.z,w2.w};
    v2f w3a={w3.x,w3.y}, w3b={w3.z,w3.w};
#pragma unroll
    for (int v=0;v<NVEC;++v){
      float4 h = *((const float4*)(hb + v*VSTRF + 4*q));   // LDS broadcast
      v2f ha={h.x,h.y}, hc={h.z,h.w};
      acc[0][v] = __builtin_elementwise_fma(w0b,hc, __builtin_elementwise_fma(w0a,ha, acc[0][v]));
      acc[1][v] = __builtin_elementwise_fma(w1b,hc, __builtin_elementwise_fma(w1a,ha, acc[1][v]));
      acc[2][v] = __builtin_elementwise_fma(w2b,hc, __builtin_elementwise_fma(w2a,ha, acc[2][v]));
      acc[3][v] = __builtin_elementwise_fma(w3b,hc, __builtin_elementwise_fma(w3a,ha, acc[3][v]));
    }
  }
#pragma unroll
  for (int v=0;v<NVEC;++v){
    float u0 = acc[0][v].x + acc[0][v].y;
    float u1 = acc[1][v].x + acc[1][v].y;
    float u2 = acc[2][v].x + acc[2][v].y;
    float u3 = acc[3][v].x + acc[3][v].y;
    u0 += __shfl_xor(u0,32);
    u1 += __shfl_xor(u1,32);
    u2 += __shfl_xor(u2,32);
    u3 += __shfl_xor(u3,32);
    zA[v] = kh ? u2 : u0;
    zB[v] = kh ? u3 : u1;
  }
}

__global__ __launch_bounds__(64)
__attribute__((amdgpu_waves_per_eu(2)))
void lnn_main(const float* __restrict__ x, const float* __restrict__ W1,
              const float* __restrict__ b1, const float* __restrict__ b2,
              const float* __restrict__ b3, const float* __restrict__ b4,
              const float* __restrict__ W5, float* __restrict__ out) {
  const int l  = threadIdx.x;
  const int o  = l & 31;
  const int kh = l >> 5;
  const int ja = o + 64*kh;
  const int jb = ja + 32;
  const int s  = blockIdx.x;           // one sample per wave

  __shared__ __align__(16) float buf[NVEC*VSTRF];  // base @0, tangents @(1+i)
  __shared__ float xs[16];

  if (l < DIM) xs[l] = x[s*DIM + l];
  __syncthreads();

  // ---- Phase 1: layer 1 (rows ja, jb) ----
  const float4* W1v = (const float4*)W1;
  float s1a, s1b;
  float w1af[8], w1bf[8];
  {
    float4 a0 = W1v[ja*4+0], a1 = W1v[ja*4+1], a2 = W1v[ja*4+2], a3 = W1v[ja*4+3];
    float4 c0 = W1v[jb*4+0], c1 = W1v[jb*4+1], c2 = W1v[jb*4+2], c3 = W1v[jb*4+3];
    float z1a = b1[ja], z1b = b1[jb];
    z1a = fmaf(a0.x, xs[0],  z1a); z1a = fmaf(a0.y, xs[1],  z1a);
    z1a = fmaf(a0.z, xs[2],  z1a); z1a = fmaf(a0.w, xs[3],  z1a);
    z1a = fmaf(a1.x, xs[4],  z1a); z1a = fmaf(a1.y, xs[5],  z1a);
    z1a = fmaf(a1.z, xs[6],  z1a); z1a = fmaf(a1.w, xs[7],  z1a);
    z1a = fmaf(a2.x, xs[8],  z1a); z1a = fmaf(a2.y, xs[9],  z1a);
    z1a = fmaf(a2.z, xs[10], z1a); z1a = fmaf(a2.w, xs[11], z1a);
    z1a = fmaf(a3.x, xs[12], z1a); z1a = fmaf(a3.y, xs[13], z1a);
    z1a = fmaf(a3.z, xs[14], z1a); z1a = fmaf(a3.w, xs[15], z1a);
    z1b = fmaf(c0.x, xs[0],  z1b); z1b = fmaf(c0.y, xs[1],  z1b);
    z1b = fmaf(c0.z, xs[2],  z1b); z1b = fmaf(c0.w, xs[3],  z1b);
    z1b = fmaf(c1.x, xs[4],  z1b); z1b = fmaf(c1.y, xs[5],  z1b);
    z1b = fmaf(c1.z, xs[6],  z1b); z1b = fmaf(c1.w, xs[7],  z1b);
    z1b = fmaf(c2.x, xs[8],  z1b); z1b = fmaf(c2.y, xs[9],  z1b);
    z1b = fmaf(c2.z, xs[10], z1b); z1b = fmaf(c2.w, xs[11], z1b);
    z1b = fmaf(c3.x, xs[12], z1b); z1b = fmaf(c3.y, xs[13], z1b);
    z1b = fmaf(c3.z, xs[14], z1b); z1b = fmaf(c3.w, xs[15], z1b);
    s1a = sigf(z1a); s1b = sigf(z1b);
    buf[ja] = spf(z1a); buf[jb] = spf(z1b);
    w1af[0]=a2.x; w1af[1]=a2.y; w1af[2]=a2.z; w1af[3]=a2.w;
    w1af[4]=a3.x; w1af[5]=a3.y; w1af[6]=a3.z; w1af[7]=a3.w;
    w1bf[0]=c2.x; w1bf[1]=c2.y; w1bf[2]=c2.z; w1bf[3]=c2.w;
    w1bf[4]=c3.x; w1bf[5]=c3.y; w1bf[6]=c3.z; w1bf[7]=c3.w;
#pragma unroll
    for (int i=0;i<8;++i){
      buf[(1+i)*VSTRF + ja] = s1a*w1af[i];     // t_h1
      buf[(1+i)*VSTRF + jb] = s1b*w1bf[i];
    }
  }
  __syncthreads();

  float zA[NVEC], zB[NVEC];

  // ---- Phase 2: layer 2 forward (PF2) ----
  gemv9f32(g_wsf + 0, buf, o, kh, zA, zB);
  float z2a = zA[0] + b2[ja], z2b = zB[0] + b2[jb];
  float t2a[8], t2b[8];
#pragma unroll
  for (int i=0;i<8;++i){ t2a[i]=zA[1+i]; t2b[i]=zB[1+i]; }
  float s2a = sigf(z2a), s2b = sigf(z2b);
  __syncthreads();
  buf[ja] = spf(z2a); buf[jb] = spf(z2b);
#pragma unroll
  for (int i=0;i<8;++i){
    buf[(1+i)*VSTRF + ja] = s2a*zA[1+i];
    buf[(1+i)*VSTRF + jb] = s2b*zB[1+i];
  }
  __syncthreads();

  // ---- Phase 3: layer 3 forward (PF3) ----
  gemv9f32(g_wsf + 32768, buf, o, kh, zA, zB);
  float z3a = zA[0] + b3[ja], z3b = zB[0] + b3[jb];
  float t3a[8], t3b[8];
#pragma unroll
  for (int i=0;i<8;++i){ t3a[i]=zA[1+i]; t3b[i]=zB[1+i]; }
  float s3a = sigf(z3a), s3b = sigf(z3b);
  __syncthreads();
  buf[ja] = spf(z3a); buf[jb] = spf(z3b);
#pragma unroll
  for (int i=0;i<8;++i){
    buf[(1+i)*VSTRF + ja] = s3a*zA[1+i];
    buf[(1+i)*VSTRF + jb] = s3b*zB[1+i];
  }
  __syncthreads();

  // ---- Phase 4+5: layer 4 forward (PF4) + head ----
  gemv9f32(g_wsf + 65536, buf, o, kh, zA, zB);
  {
    float z4a = zA[0] + b4[ja], z4b = zB[0] + b4[jb];
    float w5a = W5[ja], w5b = W5[jb];
    float sa = sigf(z4a), sb = sigf(z4b);
    float ca = w5a*sa*(1.0f-sa), cb = w5b*sb*(1.0f-sb);
    __syncthreads();
    buf[ja] = w5a*sa; buf[jb] = w5b*sb;                   // g_z4
#pragma unroll
    for (int i=0;i<8;++i){
      buf[(1+i)*VSTRF + ja] = ca*zA[1+i];                 // u_z4
      buf[(1+i)*VSTRF + jb] = cb*zB[1+i];
    }
  }
  __syncthreads();

  // ---- Phase 6: backward through W4^T (PB4) ----
  gemv9f32(g_wsf + 81920, buf, o, kh, zA, zB);
  {
    float da = s3a*(1.0f-s3a)*zA[0], db = s3b*(1.0f-s3b)*zB[0];
    __syncthreads();
    buf[ja] = zA[0]*s3a; buf[jb] = zB[0]*s3b;             // g_z3
#pragma unroll
    for (int i=0;i<8;++i){
      buf[(1+i)*VSTRF + ja] = fmaf(zA[1+i], s3a, da*t3a[i]);  // u_z3
      buf[(1+i)*VSTRF + jb] = fmaf(zB[1+i], s3b, db*t3b[i]);
    }
  }
  __syncthreads();

  // ---- Phase 7: backward through W3^T (PB3) ----
  gemv9f32(g_wsf + 49152, buf, o, kh, zA, zB);
  {
    float da = s2a*(1.0f-s2a)*zA[0], db = s2b*(1.0f-s2b)*zB[0];
    __syncthreads();
    buf[ja] = zA[0]*s2a; buf[jb] = zB[0]*s2b;             // g_z2
#pragma unroll
    for (int i=0;i<8;++i){
      buf[(1+i)*VSTRF + ja] = fmaf(zA[1+i], s2a, da*t2a[i]);  // u_z2
      buf[(1+i)*VSTRF + jb] = fmaf(zB[1+i], s2b, db*t2b[i]);
    }
  }
  __syncthreads();

  // ---- Phase 8: backward through W2^T (PB2); W1 tangent cols from phase-1 regs ----
  gemv9f32(g_wsf + 16384, buf, o, kh, zA, zB);
  {
    float da = s1a*(1.0f-s1a)*zA[0], db = s1b*(1.0f-s1b)*zB[0];
    __syncthreads();
    buf[ja] = zA[0]*s1a; buf[jb] = zB[0]*s1b;             // g_z1
#pragma unroll
    for (int i=0;i<8;++i){
      buf[(1+i)*VSTRF + ja] = fmaf(zA[1+i], s1a, da*w1af[i]); // u_z1
      buf[(1+i)*VSTRF + jb] = fmaf(zB[1+i], s1b, db*w1bf[i]);
    }
  }
  __syncthreads();

  // ---- Phase 9: H rows (8..15) + J via W1^T (PB1), pk-fma over k-pairs ----
  float hA, hB, hJ;
  {
    const int m = l & 15, d = l >> 4;
    const float4* P1 = (const float4*)(g_wsf + 98304);
    v2f aA={0.0f,0.0f}, aB={0.0f,0.0f}, aJ={0.0f,0.0f};
#pragma unroll 4
    for (int q=0; q<32; ++q){
      float4 wq = P1[q*DIM + m];          // W1[4q..4q+3][m]
      v2f wa={wq.x,wq.y}, wb={wq.z,wq.w};
      float4 u0 = *((const float4*)(buf + (1+d)*VSTRF + 4*q));
      float4 u1 = *((const float4*)(buf + (5+d)*VSTRF + 4*q));
      float4 gg = *((const float4*)(buf + 4*q));
      aA = __builtin_elementwise_fma(wb,(v2f){u0.z,u0.w}, __builtin_elementwise_fma(wa,(v2f){u0.x,u0.y}, aA));
      aB = __builtin_elementwise_fma(wb,(v2f){u1.z,u1.w}, __builtin_elementwise_fma(wa,(v2f){u1.x,u1.y}, aB));
      aJ = __builtin_elementwise_fma(wb,(v2f){gg.z,gg.w}, __builtin_elementwise_fma(wa,(v2f){gg.x,gg.y}, aJ));
    }
    hA = aA.x + aA.y;   // lane (m,d): H[8+d][m]
    hB = aB.x + aB.y;   // H[8+4+d][m]
    hJ = aJ.x + aJ.y;   // J[m]
  }

  // ---- Phase 10: y = pinv(B) @ (J[:8] - C qdot); all-f32 Jacobi solve ----
  {
    const int r = l >> 3, c = l & 7;
    float BvA = __shfl(hA, ((r&3)*16) + 8 + c);
    float BvB = __shfl(hB, ((r&3)*16) + 8 + c);
    float Bv  = (r < 4) ? BvA : BvB;              // B[r][c] = H[8+r][8+c]
    float CrA = __shfl(hA, ((r&3)*16) + c);
    float CrB = __shfl(hB, ((r&3)*16) + c);
    float Cr  = (r < 4) ? CrA : CrB;              // C[r][c] = H[8+r][c]
    float Jr  = __shfl(hJ, r);                    // J[r]
    float p0 = Cr * xs[8 + c];
    p0 += __shfl_xor(p0, 1); p0 += __shfl_xor(p0, 2); p0 += __shfl_xor(p0, 4);
    float rhs = Jr - p0;

    // symmetrize
    float Bt = __shfl(Bv, c*8 + r);
    float Am = 0.5f*(Bv + Bt);
    float Vm = (r == c) ? 1.0f : 0.0f;

    // Parallel-order (round-robin) Jacobi: 4 disjoint pairs/step, 7 steps/sweep, 4 sweeps.
    for (int sweep = 0; sweep < 4; ++sweep) {
#pragma unroll
      for (int rr = 0; rr < 7; ++rr) {
        int pc = (c == 7) ? rr : ((c == rr) ? 7 : (2*rr + 7 - c) % 7);
        int cp = min(c, pc), cq = max(c, pc);
        float App = __shfl(Am, cp*8+cp);
        float Aqq = __shfl(Am, cq*8+cq);
        float Apq = __shfl(Am, cp*8+cq);
        float tau = (Aqq - App) / (2.0f*Apq);
        float tt  = (tau >= 0.0f ? 1.0f : -1.0f) / (fabsf(tau) + sqrtf(1.0f + tau*tau));
        float cth = 1.0f / sqrtf(1.0f + tt*tt);
        float sth = tt * cth;
        if (fabsf(Apq) < 1e-30f) { cth = 1.0f; sth = 0.0f; }   // guard 0/0 -> NaN
        float cthr = __shfl(cth, r*8+r);
        float sthr = __shfl(sth, r*8+r);
        // column rotation: M = A*G
        float Arp = __shfl(Am, r*8+cp);
        float Arq = __shfl(Am, r*8+cq);
        float colv = (c == cp) ? (cth*Arp - sth*Arq) : (sth*Arp + cth*Arq);
        // row rotation: A = G^T*M
        int pr2 = (r == 7) ? rr : ((r == rr) ? 7 : (2*rr + 7 - r) % 7);
        int rp = min(r, pr2), rq = max(r, pr2);
        float Mpc = __shfl(colv, rp*8+c);
        float Mqc = __shfl(colv, rq*8+c);
        Am = (r == rp) ? (cthr*Mpc - sthr*Mqc) : (sthr*Mpc + cthr*Mqc);
        // V = V*G
        float Vrp = __shfl(Vm, r*8+cp);
        float Vrq = __shfl(Vm, r*8+cq);
        Vm = (c == cp) ? (cth*Vrp - sth*Vrq) : (sth*Vrp + cth*Vrq);
      }
    }

    // eigenvalue for this lane's column, and sigma_max = max |diag|
    float lam_c = __shfl(Am, c*8 + c);
    float adiag = (r == c) ? fabsf(Am) : 0.0f;
#pragma unroll
    for (int off = 32; off; off >>= 1) adiag = fmaxf(adiag, __shfl_xor(adiag, off));
    float cutoff = 9.5367431640625e-06f * adiag;   // 10*max(M,N)*eps_f32 * sigma_max

    // p_c = sum_r V[r][c]*rhs_r
    float pr = Vm * rhs;
    pr += __shfl_xor(pr, 8); pr += __shfl_xor(pr, 16); pr += __shfl_xor(pr, 32);
    float w = (fabsf(lam_c) > cutoff) ? (pr / lam_c) : 0.0f;
    // y_r = sum_c V[r][c]*w_c
    float yr = Vm * w;
    yr += __shfl_xor(yr, 1); yr += __shfl_xor(yr, 2); yr += __shfl_xor(yr, 4);
    if (c == 0) out[s*NPAR + r] = yr;
  }
}

extern "C" void kernel_launch(void* const* d_in, const int* in_sizes, int n_in,
                              void* d_out, int out_size, void* d_ws, size_t ws_size,
                              hipStream_t stream) {
  (void)in_sizes; (void)n_in; (void)out_size; (void)d_ws; (void)ws_size;
  const float* x  = (const float*)d_in[0];
  const float* W1 = (const float*)d_in[1];
  const float* b1 = (const float*)d_in[2];
  const float* W2 = (const float*)d_in[3];
  const float* b2 = (const float*)d_in[4];
  const float* W3 = (const float*)d_in[5];
  const float* b3 = (const float*)d_in[6];
  const float* W4 = (const float*)d_in[7];
  const float* b4 = (const float*)d_in[8];
  const float* W5 = (const float*)d_in[9];
  float* out = (float*)d_out;

  pack_weights<<<200, 256, 0, stream>>>(W1, W2, W3, W4);
  lnn_main<<<BATCH, 64, 0, stream>>>(x, W1, b1, b2, b3, b4, W5, out);
}